// Round 16
// baseline (1143.033 us; speedup 1.0000x reference)
//
#include <hip/hip_runtime.h>
#include <hip/hip_bf16.h>
#include <stdint.h>

// ---------------------------------------------------------------------------
// TopKAutoEncoder forward, MI355X.
// acts = (x - pre_bias) @ W_enc + latent_bias   [16384 x 4096]
// top-64/row (exact selection vs ref), relu, @ W_dec + pre_bias.
//
// R16 GEMM: R13 pipeline/layout with 32x32x16 MFMAs and a DOUBLY-BALANCED
// chunk swizzle x(r) = ((r>>1)&3) ^ ((r>>3)&3):
//  - stride-8 lane classes {j,j+8,..}: term1 const, term2 spans 0..3 -> 2-way
//  - consecutive-16 quarters: x hits each value 2x per parity -> 2-way
// (2-way = free, m136; R2/R14/R15 failures + R13 success pin this model:
// wave64 b128 must balance BOTH structures.)
// acts fp16 into d_out's first half. Merged preprocess. Two-level-histogram
// topk + fused fp64 rescue. bf16 sparse reconstruct.
// ---------------------------------------------------------------------------

typedef _Float16 half8 __attribute__((ext_vector_type(8)));
typedef float f32x16 __attribute__((ext_vector_type(16)));
typedef unsigned short ushort8 __attribute__((ext_vector_type(8)));

#define B_ROWS 16384
#define D_DIM  4096
#define TOPK   64
#define MARGIN 0.25f
#define KT64   (D_DIM / 64)   // 64 K-tiles of BK=64

__device__ __forceinline__ void gload_lds16(const void* g, void* l) {
  __builtin_amdgcn_global_load_lds(
      (const __attribute__((address_space(1))) unsigned int*)g,
      (__attribute__((address_space(3))) unsigned int*)l, 16, 0, 0);
}

__device__ __forceinline__ unsigned short f2bf(float f) {
  unsigned u = __float_as_uint(f);
  unsigned r = (u + 0x7fffu + ((u >> 16) & 1u)) >> 16;
  return (unsigned short)r;
}

// --------------------- merged preprocess (one launch) ----------------------

__global__ __launch_bounds__(256) void preprocess(
    const float* __restrict__ x, const float* __restrict__ pre_bias,
    const float* __restrict__ W_enc, const float* __restrict__ W_dec,
    _Float16* __restrict__ Xh, _Float16* __restrict__ WhT,
    float* __restrict__ WT, unsigned short* __restrict__ Wd) {
  __shared__ float tile[64][65];
  const int bid = blockIdx.x;
  const int tid = threadIdx.x;
  if (bid < 32768) {
    size_t g = ((size_t)bid * 256 + tid) * 8;
    int col = (int)(g & (D_DIM - 1));
    float4 a = *(const float4*)(x + g);
    float4 b = *(const float4*)(x + g + 4);
    float4 p = *(const float4*)(pre_bias + col);
    float4 q = *(const float4*)(pre_bias + col + 4);
    half8 h;
    h[0] = (_Float16)(a.x - p.x); h[1] = (_Float16)(a.y - p.y);
    h[2] = (_Float16)(a.z - p.z); h[3] = (_Float16)(a.w - p.w);
    h[4] = (_Float16)(b.x - q.x); h[5] = (_Float16)(b.y - q.y);
    h[6] = (_Float16)(b.z - q.z); h[7] = (_Float16)(b.w - q.w);
    *(half8*)(Xh + g) = h;
  } else if (bid < 36864) {
    const int b2 = bid - 32768;
    const int bx = b2 & 63, by = b2 >> 6;
    const int tx = tid & 63, ty4 = tid >> 6;
    #pragma unroll 4
    for (int i = 0; i < 16; ++i) {
      int r = ty4 * 16 + i;
      tile[r][tx] = W_enc[(size_t)(by * 64 + r) * D_DIM + bx * 64 + tx];
    }
    __syncthreads();
    #pragma unroll 4
    for (int i = 0; i < 16; ++i) {
      int r = ty4 * 16 + i;
      float v = tile[tx][r];
      size_t o = (size_t)(bx * 64 + r) * D_DIM + by * 64 + tx;
      WT[o] = v;
      WhT[o] = (_Float16)v;
    }
  } else {
    size_t g = ((size_t)(bid - 36864) * 256 + tid) * 8;
    float4 a = *(const float4*)(W_dec + g);
    float4 b = *(const float4*)(W_dec + g + 4);
    ushort8 v;
    v[0] = f2bf(a.x); v[1] = f2bf(a.y); v[2] = f2bf(a.z); v[3] = f2bf(a.w);
    v[4] = f2bf(b.x); v[5] = f2bf(b.y); v[6] = f2bf(b.z); v[7] = f2bf(b.w);
    *(ushort8*)(Wd + g) = v;
  }
}

// ------------------------------- fp16 GEMM ---------------------------------
// LDS (halves): buffer d at d*32768; A kh-region at +kh*8192, B kh-region
// at +16384+kh*8192; region = 256 rows x 32 halves (4 chunks of 16B).
// Swizzle: phys slot (r,p) holds logical chunk p ^ x(r),
// x(r) = ((r>>1)&3) ^ ((r>>3)&3); read chunk c of row r at phys c ^ x(r).
// Wave offsets (x32/x64) drop out of both terms. Bank-group balance:
// 2-way in stride-8 classes AND consecutive-16 quarters (free per m136).
// Sync: stage(t+1) at body start into buf (t+1)&1 (last readers finished
// >=1 barrier ago), compute tile t, vmcnt(0) drain (stage issued ~1 full
// body earlier -> ~free), barrier. Prologue keeps wait->barrier (R4).

#define STAGE64(T)                                                             \
  do {                                                                         \
    const int bb_ = ((T) & 1) * 32768;                                         \
    const int kk_ = (T) * 64;                                                  \
    gload_lds16(aSrc + kk_, ldsbuf + bb_ + dstL);                              \
    gload_lds16(aSrc + kk_ + 32, ldsbuf + bb_ + 8192 + dstL);                  \
    gload_lds16(bSrc + kk_, ldsbuf + bb_ + 16384 + dstL);                      \
    gload_lds16(bSrc + kk_ + 32, ldsbuf + bb_ + 24576 + dstL);                 \
  } while (0)

#define BODY64(T, DOSTAGE)                                                     \
  do {                                                                         \
    if (DOSTAGE) STAGE64((T) + 1);                                             \
    const int bb_ = ((T) & 1) * 32768;                                         \
    _Pragma("unroll") for (int kh = 0; kh < 2; ++kh) {                         \
      const int rg_ = bb_ + kh * 8192;                                         \
      _Pragma("unroll") for (int kw = 0; kw < 2; ++kw) {                       \
        const int p8_ = (((kw * 2 + hi) ^ xsw) & 3) * 8;                       \
        half8 a0 = *(const half8*)(ldsbuf + rg_ + baseA0 + p8_);               \
        half8 a1 = *(const half8*)(ldsbuf + rg_ + baseA1 + p8_);               \
        half8 b0 = *(const half8*)(ldsbuf + rg_ + baseB0 + p8_);               \
        half8 b1 = *(const half8*)(ldsbuf + rg_ + baseB1 + p8_);               \
        __builtin_amdgcn_s_setprio(1);                                         \
        acc00 =                                                                \
            __builtin_amdgcn_mfma_f32_32x32x16_f16(a0, b0, acc00, 0, 0, 0);    \
        acc01 =                                                                \
            __builtin_amdgcn_mfma_f32_32x32x16_f16(a0, b1, acc01, 0, 0, 0);    \
        acc10 =                                                                \
            __builtin_amdgcn_mfma_f32_32x32x16_f16(a1, b0, acc10, 0, 0, 0);    \
        acc11 =                                                                \
            __builtin_amdgcn_mfma_f32_32x32x16_f16(a1, b1, acc11, 0, 0, 0);    \
        __builtin_amdgcn_s_setprio(0);                                         \
      }                                                                        \
    }                                                                          \
    asm volatile("s_waitcnt vmcnt(0)" ::: "memory");                           \
    __builtin_amdgcn_s_barrier();                                              \
    asm volatile("" ::: "memory");                                             \
  } while (0)

__global__ __launch_bounds__(1024, 4) void gemm_f16(
    const _Float16* __restrict__ A, const _Float16* __restrict__ Bt,
    const float* __restrict__ latent_bias, _Float16* __restrict__ C) {
  extern __shared__ _Float16 ldsbuf[];   // 2 bufs x 32768 halves (128KB)

  const int tid = threadIdx.x;
  const int lane = tid & 63;
  const int l31 = lane & 31, hi = lane >> 5;
  const int wave = tid >> 6;                    // 0..15
  const int wm = wave >> 2, wn = wave & 3;      // 4M x 4N, 64x64 per wave

  // XCD swizzle; grid = 1024, divisible by 8 -> bijective.
  int bid = blockIdx.x;
  int swz = (bid & 7) * (1024 >> 3) + (bid >> 3);
  const int bmBase = (swz >> 4) * 256;
  const int bnBase = (swz & 15) * 256;

  // staging: slot tid of each (operand, kh) region; row r = tid>>2,
  // phys chunk p = tid&3 holds logical chunk p ^ x(r),
  // x(r) = ((r>>1)&3)^((r>>3)&3) = ((tid>>3)&3)^((tid>>5)&3).
  const int xst = ((tid >> 3) & 3) ^ ((tid >> 5) & 3);
  const int s = tid ^ xst;  // xst in 0..3 -> flips chunk bits only
  const _Float16* aSrc = A + (size_t)(bmBase + (s >> 2)) * D_DIM + (s & 3) * 8;
  const _Float16* bSrc = Bt + (size_t)(bnBase + (s >> 2)) * D_DIM + (s & 3) * 8;
  const int dstL = tid * 8;

  // fragment read: row R = woff + l31 -> x(R) = ((l31>>1)&3)^((l31>>3)&3)
  const int xsw = ((l31 >> 1) & 3) ^ ((l31 >> 3) & 3);
  const int baseA0 = (wm * 64 + l31) * 32;            // mi2 = 0
  const int baseA1 = (wm * 64 + 32 + l31) * 32;       // mi2 = 1
  const int baseB0 = 16384 + (wn * 64 + l31) * 32;    // nj2 = 0
  const int baseB1 = 16384 + (wn * 64 + 32 + l31) * 32;

  f32x16 acc00, acc01, acc10, acc11;
  #pragma unroll
  for (int i = 0; i < 16; ++i) {
    acc00[i] = 0.f; acc01[i] = 0.f; acc10[i] = 0.f; acc11[i] = 0.f;
  }

  // prologue: stage tile 0; wait own loads; barrier (cross-wave visibility)
  STAGE64(0);
  asm volatile("s_waitcnt vmcnt(0)" ::: "memory");
  __builtin_amdgcn_s_barrier();
  asm volatile("" ::: "memory");

  for (int t = 0; t < KT64 - 1; ++t) BODY64(t, true);
  BODY64(KT64 - 1, false);

  // epilogue: 32x32 C/D mapping col=lane&31, row=(r&3)+8*(r>>2)+4*(lane>>5)
  // (HW-verified R6/R14/R15 via absmax); fp16 store.
  const int crow0 = bmBase + wm * 64;
  const int ccol0 = bnBase + wn * 64;
  const float lb0 = latent_bias[ccol0 + l31];
  const float lb1 = latent_bias[ccol0 + 32 + l31];
  #pragma unroll
  for (int r = 0; r < 16; ++r) {
    const int rr = (r & 3) + 8 * (r >> 2) + 4 * hi;
    C[(size_t)(crow0 + rr) * D_DIM + ccol0 + l31] = (_Float16)(acc00[r] + lb0);
    C[(size_t)(crow0 + rr) * D_DIM + ccol0 + 32 + l31] =
        (_Float16)(acc01[r] + lb1);
    C[(size_t)(crow0 + 32 + rr) * D_DIM + ccol0 + l31] =
        (_Float16)(acc10[r] + lb0);
    C[(size_t)(crow0 + 32 + rr) * D_DIM + ccol0 + 32 + l31] =
        (_Float16)(acc11[r] + lb1);
  }
}

// ------------- fused two-level-histogram top-k + fp64 rescue ---------------
// acts fp16 (quantization +-0.0625 at |v|<256); MARGIN=0.25 covers GEMM
// error (~0.16, 6-sigma) + quantization. Coarse 256 x 4.0 -> rank-refined
// fine 256 x 0.015625 -> T64 bracket [Tlo,Thi). Members: v > Thi+M
// (provably in exact top-64, < 64 of them). Zone: [Tlo-M, Thi+M]. Fast
// path: |zone| == need -> emit. Else fp64 dots (wave-per-candidate).

__global__ __launch_bounds__(256) void topk_full(
    const _Float16* __restrict__ acts, const float* __restrict__ x,
    const float* __restrict__ WT, const float* __restrict__ pre_bias,
    const float* __restrict__ latent_bias, float* __restrict__ vals,
    int* __restrict__ idxs) {
  const int row = blockIdx.x;
  const int tid = threadIdx.x;
  const int lane = tid & 63, wave = tid >> 6;
  __shared__ int hist[256];
  __shared__ int suf[256];
  __shared__ int sred[8];
  __shared__ int ambL[128];
  __shared__ double exv[128];
  const _Float16* arow = acts + (size_t)row * D_DIM;
  float fv[16];
  {
    half8 h0 = *(const half8*)(arow + tid * 8);
    half8 h1 = *(const half8*)(arow + 2048 + tid * 8);
    #pragma unroll
    for (int j = 0; j < 8; ++j) {
      fv[j] = (float)h0[j];
      fv[8 + j] = (float)h1[j];
    }
  }
  // ---- coarse pass ----
  hist[tid] = 0;
  __syncthreads();
  #pragma unroll
  for (int e = 0; e < 16; ++e) {
    int b = (int)((fv[e] + 512.0f) * 0.25f);
    b = b < 0 ? 0 : (b > 255 ? 255 : b);
    atomicAdd(&hist[b], 1);
  }
  __syncthreads();
  int c = hist[tid];
  int sfx = c;
  #pragma unroll
  for (int off = 1; off < 64; off <<= 1) {
    int y = __shfl_down(sfx, off);
    if (lane + off < 64) sfx += y;
  }
  if (lane == 0) sred[wave] = sfx;
  __syncthreads();
  {
    int after = 0;
    for (int w = wave + 1; w < 4; ++w) after += sred[w];
    sfx += after;  // count of values in bins >= tid
  }
  suf[tid] = sfx;
  int cnd = (sfx >= TOPK) ? tid : -1;
  #pragma unroll
  for (int off = 32; off; off >>= 1) {
    int y = __shfl_down(cnd, off);
    cnd = y > cnd ? y : cnd;
  }
  if (lane == 0) sred[4 + wave] = cnd;
  __syncthreads();
  int cb;
  {
    int m0 = sred[4] > sred[5] ? sred[4] : sred[5];
    int m1 = sred[6] > sred[7] ? sred[6] : sred[7];
    cb = m0 > m1 ? m0 : m1;  // exists: suffix(0) = 4096 >= 64
  }
  const int S_above = (cb < 255) ? suf[cb + 1] : 0;
  const int rrank = TOPK - S_above;  // in [1, count(cb)]
  const float Clo = cb * 4.0f - 512.0f;
  // ---- fine pass (reuse hist/sred) ----
  __syncthreads();
  hist[tid] = 0;
  __syncthreads();
  #pragma unroll
  for (int e = 0; e < 16; ++e) {
    int bc = (int)((fv[e] + 512.0f) * 0.25f);
    bc = bc < 0 ? 0 : (bc > 255 ? 255 : bc);
    if (bc == cb) {
      int fb = (int)((fv[e] - Clo) * 64.0f);
      fb = fb < 0 ? 0 : (fb > 255 ? 255 : fb);
      atomicAdd(&hist[fb], 1);
    }
  }
  __syncthreads();
  int cf = hist[tid];
  int sfx2 = cf;
  #pragma unroll
  for (int off = 1; off < 64; off <<= 1) {
    int y = __shfl_down(sfx2, off);
    if (lane + off < 64) sfx2 += y;
  }
  if (lane == 0) sred[wave] = sfx2;
  __syncthreads();
  {
    int after = 0;
    for (int w = wave + 1; w < 4; ++w) after += sred[w];
    sfx2 += after;
  }
  int cnd2 = (sfx2 >= rrank) ? tid : -1;
  #pragma unroll
  for (int off = 32; off; off >>= 1) {
    int y = __shfl_down(cnd2, off);
    cnd2 = y > cnd2 ? y : cnd2;
  }
  if (lane == 0) sred[4 + wave] = cnd2;
  __syncthreads();
  int fb;
  {
    int m0 = sred[4] > sred[5] ? sred[4] : sred[5];
    int m1 = sred[6] > sred[7] ? sred[6] : sred[7];
    fb = m0 > m1 ? m0 : m1;  // exists: fine suffix(0) = count(cb) >= rrank
  }
  const float Tlo = (cb == 0 && fb == 0) ? -1e30f : (Clo + fb * 0.015625f);
  const float Thi =
      (cb == 255 && fb == 255) ? 1e30f : (Clo + (fb + 1) * 0.015625f);
  const float vhi = Thi + MARGIN;
  const float vlo = Tlo - MARGIN;
  // ---- classify + emit ----
  int mC = 0, aC = 0;
  #pragma unroll
  for (int i = 0; i < 16; ++i) {
    float v = fv[i];
    if (v > vhi) ++mC;
    else if (v >= vlo) ++aC;
  }
  int xs = mC | (aC << 16);
  #pragma unroll
  for (int off = 1; off < 64; off <<= 1) {
    int y = __shfl_up(xs, off);
    if (lane >= off) xs += y;
  }
  __syncthreads();  // sred reuse
  if (lane == 63) sred[wave] = xs;
  __syncthreads();
  int base = 0;
  for (int w = 0; w < 4; ++w)
    if (w < wave) base += sred[w];
  int tot = sred[0] + sred[1] + sred[2] + sred[3];
  int incl = base + xs;
  int mp = (incl & 0xffff) - mC;
  int ap = (incl >> 16) - aC;
  int mTot = tot & 0xffff, aTot = tot >> 16;
  const int need = TOPK - mTot;      // >= 1 provably
  const bool fast = (aTot == need);  // zone exactly fills the remainder
  #pragma unroll
  for (int e = 0; e < 16; ++e) {
    float v = fv[e];
    int d = (e < 8) ? (tid * 8 + e) : (2048 + tid * 8 + (e - 8));
    if (v > vhi) {
      vals[(size_t)row * TOPK + mp] = fmaxf(v, 0.0f);
      idxs[(size_t)row * TOPK + mp] = d;
      ++mp;
    } else if (v >= vlo) {
      if (fast) {
        vals[(size_t)row * TOPK + mTot + ap] = fmaxf(v, 0.0f);
        idxs[(size_t)row * TOPK + mTot + ap] = d;
      } else if (ap < 128) {
        ambL[ap] = d;
      }
      ++ap;
    }
  }
  if (fast) return;
  // ---- fused fp64 rescue ----
  __syncthreads();  // ambL visible block-wide
  const int sN = aTot > 128 ? 128 : aTot;
  const float* xr = x + (size_t)row * D_DIM;
  for (int cc = wave; cc < sN; cc += 4) {
    int d = ambL[cc];
    const float* wrow = WT + (size_t)d * D_DIM;
    double acc = 0.0;
    #pragma unroll 4
    for (int t = 0; t < 16; ++t) {
      int k0 = t * 256 + lane * 4;
      float4 xv = *(const float4*)(xr + k0);
      float4 pv = *(const float4*)(pre_bias + k0);
      float4 wv = *(const float4*)(wrow + k0);
      acc = fma((double)xv.x - (double)pv.x, (double)wv.x, acc);
      acc = fma((double)xv.y - (double)pv.y, (double)wv.y, acc);
      acc = fma((double)xv.z - (double)pv.z, (double)wv.z, acc);
      acc = fma((double)xv.w - (double)pv.w, (double)wv.w, acc);
    }
    #pragma unroll
    for (int off = 32; off; off >>= 1) acc += __shfl_down(acc, off);
    if (lane == 0) exv[cc] = acc + (double)latent_bias[d];
  }
  __syncthreads();
  if (tid == 0) {
    for (int t = 0; t < need; ++t) {
      double best = -1.0e300; int besti = 1 << 30; int bestc = -1;
      for (int cc = 0; cc < sN; ++cc) {
        double v = exv[cc];
        int d = ambL[cc];
        if (v > best || (v == best && d < besti)) {
          best = v; besti = d; bestc = cc;
        }
      }
      vals[(size_t)row * TOPK + mTot + t] = fmaxf((float)best, 0.0f);
      idxs[(size_t)row * TOPK + mTot + t] = besti;
      exv[bestc] = -1.0e300;
    }
  }
}

// ----------------------------- reconstruct ---------------------------------

__global__ __launch_bounds__(256) void reconstruct(
    const unsigned short* __restrict__ Wd, const float* __restrict__ vals,
    const int* __restrict__ idxs, const float* __restrict__ pre_bias,
    float* __restrict__ out) {
  const int bid = blockIdx.x;
  const int cb = bid & 7, rowblk = bid >> 3;
  const int tid = threadIdx.x, lane = tid & 63, wave = tid >> 6;
  const int row = rowblk * 4 + wave;
  const int col0 = cb * 512 + lane * 8;
  __shared__ float sval[256];
  __shared__ int sidx[256];
  sval[tid] = vals[(size_t)(rowblk * 4 + (tid >> 6)) * TOPK + (tid & 63)];
  sidx[tid] = idxs[(size_t)(rowblk * 4 + (tid >> 6)) * TOPK + (tid & 63)];
  __syncthreads();
  float acc[8];
  float4 p0 = *(const float4*)(pre_bias + col0);
  float4 p1 = *(const float4*)(pre_bias + col0 + 4);
  acc[0] = p0.x; acc[1] = p0.y; acc[2] = p0.z; acc[3] = p0.w;
  acc[4] = p1.x; acc[5] = p1.y; acc[6] = p1.z; acc[7] = p1.w;
  #pragma unroll 4
  for (int k = 0; k < TOPK; ++k) {
    float v = sval[wave * 64 + k];
    int d = sidx[wave * 64 + k];
    ushort8 w = *(const ushort8*)(Wd + (size_t)d * D_DIM + col0);
    #pragma unroll
    for (int j = 0; j < 8; ++j)
      acc[j] = fmaf(v, __uint_as_float(((unsigned)w[j]) << 16), acc[j]);
  }
  float4 o0 = {acc[0], acc[1], acc[2], acc[3]};
  float4 o1 = {acc[4], acc[5], acc[6], acc[7]};
  *(float4*)(out + (size_t)row * D_DIM + col0) = o0;
  *(float4*)(out + (size_t)row * D_DIM + col0 + 4) = o1;
}

// ------------------------------- launcher ----------------------------------

extern "C" void kernel_launch(void* const* d_in, const int* in_sizes, int n_in,
                              void* d_out, int out_size, void* d_ws,
                              size_t ws_size, hipStream_t stream) {
  const float* x           = (const float*)d_in[0];
  // d_in[1] = ema_frequency_counter (unused by reference)
  const float* W_enc       = (const float*)d_in[2];
  const float* W_dec       = (const float*)d_in[3];
  const float* pre_bias    = (const float*)d_in[4];
  const float* latent_bias = (const float*)d_in[5];
  float* out = (float*)d_out;
  // fp16 acts alias d_out's first half; fully consumed by topk_full before
  // reconstruct overwrites all of out.
  _Float16* actsH = (_Float16*)d_out;
  char* ws = (char*)d_ws;
  size_t off = 0;
  auto alloc = [&](size_t bytes) {
    size_t o = off;
    off = (off + bytes + 255) & ~(size_t)255;
    return o;
  };
  _Float16* Xh        = (_Float16*)(ws + alloc((size_t)B_ROWS * D_DIM * 2));
  _Float16* WhT       = (_Float16*)(ws + alloc((size_t)D_DIM * D_DIM * 2));
  float* WT           = (float*)(ws + alloc((size_t)D_DIM * D_DIM * 4));
  unsigned short* Wd  = (unsigned short*)(ws + alloc((size_t)D_DIM * D_DIM * 2));
  float* vals         = (float*)(ws + alloc((size_t)B_ROWS * TOPK * 4));
  int* idxs           = (int*)(ws + alloc((size_t)B_ROWS * TOPK * 4));
  (void)ws_size; (void)in_sizes; (void)n_in; (void)out_size;

  // allow 128KB dynamic LDS for the GEMM (cheap, deterministic, idempotent)
  (void)hipFuncSetAttribute((const void*)gemm_f16,
                            hipFuncAttributeMaxDynamicSharedMemorySize,
                            131072);

  preprocess<<<45056, 256, 0, stream>>>(x, pre_bias, W_enc, W_dec,
                                        Xh, WhT, WT, Wd);
  gemm_f16<<<(B_ROWS / 256) * (D_DIM / 256), 1024, 131072, stream>>>(
      Xh, WhT, latent_bias, actsH);
  topk_full<<<B_ROWS, 256, 0, stream>>>(actsH, x, WT, pre_bias, latent_bias,
                                        vals, idxs);
  reconstruct<<<(B_ROWS / 4) * 8, 256, 0, stream>>>(Wd, vals, idxs, pre_bias,
                                                    out);
}

// Round 17
// 1062.160 us; speedup vs baseline: 1.0761x; 1.0761x over previous
//
#include <hip/hip_runtime.h>
#include <hip/hip_bf16.h>
#include <stdint.h>

// ---------------------------------------------------------------------------
// TopKAutoEncoder forward, MI355X.  (R17 = R13 verbatim, the measured best:
// 1078 us. R14/R15/R16 established that 32x32 MFMA fragment reads conflict
// in this LDS layout family regardless of chunk swizzle; 16x16 quarter
// pattern measures 0 conflicts. Reverting to the verified optimum.)
//
// GEMM: 256x256 tile, 1024 thr / 16 waves (4Mx4N, 64x64 out), BK=64
// K-tiles, 2-buffer LDS pipeline (2 x 64KB), stage-early + vmcnt(0) drain
// (stage issued ~1 full body earlier -> ~free) + 1 barrier/tile, chunk-XOR
// swizzle (0 bank conflicts), XCD swizzle, setprio. acts stored fp16 into
// d_out's first half. Merged preprocess. Two-level-histogram topk + fused
// fp64 boundary rescue. bf16 sparse reconstruct, XCD-L2-resident slabs.
// ---------------------------------------------------------------------------

typedef _Float16 half8 __attribute__((ext_vector_type(8)));
typedef float f32x4 __attribute__((ext_vector_type(4)));
typedef unsigned short ushort8 __attribute__((ext_vector_type(8)));

#define B_ROWS 16384
#define D_DIM  4096
#define TOPK   64
#define MARGIN 0.25f
#define KT64   (D_DIM / 64)   // 64 K-tiles of BK=64

__device__ __forceinline__ void gload_lds16(const void* g, void* l) {
  __builtin_amdgcn_global_load_lds(
      (const __attribute__((address_space(1))) unsigned int*)g,
      (__attribute__((address_space(3))) unsigned int*)l, 16, 0, 0);
}

__device__ __forceinline__ unsigned short f2bf(float f) {
  unsigned u = __float_as_uint(f);
  unsigned r = (u + 0x7fffu + ((u >> 16) & 1u)) >> 16;
  return (unsigned short)r;
}

// --------------------- merged preprocess (one launch) ----------------------
// blocks [0, 32768):   conv_x   -- Xh = fp16(x - pre_bias)
// blocks [32768,36864): transp_w -- WhT/WT = W_enc^T (fp16 + fp32)
// blocks [36864,45056): conv_wd  -- Wd = bf16(W_dec)

__global__ __launch_bounds__(256) void preprocess(
    const float* __restrict__ x, const float* __restrict__ pre_bias,
    const float* __restrict__ W_enc, const float* __restrict__ W_dec,
    _Float16* __restrict__ Xh, _Float16* __restrict__ WhT,
    float* __restrict__ WT, unsigned short* __restrict__ Wd) {
  __shared__ float tile[64][65];
  const int bid = blockIdx.x;
  const int tid = threadIdx.x;
  if (bid < 32768) {
    size_t g = ((size_t)bid * 256 + tid) * 8;
    int col = (int)(g & (D_DIM - 1));
    float4 a = *(const float4*)(x + g);
    float4 b = *(const float4*)(x + g + 4);
    float4 p = *(const float4*)(pre_bias + col);
    float4 q = *(const float4*)(pre_bias + col + 4);
    half8 h;
    h[0] = (_Float16)(a.x - p.x); h[1] = (_Float16)(a.y - p.y);
    h[2] = (_Float16)(a.z - p.z); h[3] = (_Float16)(a.w - p.w);
    h[4] = (_Float16)(b.x - q.x); h[5] = (_Float16)(b.y - q.y);
    h[6] = (_Float16)(b.z - q.z); h[7] = (_Float16)(b.w - q.w);
    *(half8*)(Xh + g) = h;
  } else if (bid < 36864) {
    const int b2 = bid - 32768;
    const int bx = b2 & 63, by = b2 >> 6;
    const int tx = tid & 63, ty4 = tid >> 6;
    #pragma unroll 4
    for (int i = 0; i < 16; ++i) {
      int r = ty4 * 16 + i;
      tile[r][tx] = W_enc[(size_t)(by * 64 + r) * D_DIM + bx * 64 + tx];
    }
    __syncthreads();
    #pragma unroll 4
    for (int i = 0; i < 16; ++i) {
      int r = ty4 * 16 + i;
      float v = tile[tx][r];
      size_t o = (size_t)(bx * 64 + r) * D_DIM + by * 64 + tx;
      WT[o] = v;
      WhT[o] = (_Float16)v;
    }
  } else {
    size_t g = ((size_t)(bid - 36864) * 256 + tid) * 8;
    float4 a = *(const float4*)(W_dec + g);
    float4 b = *(const float4*)(W_dec + g + 4);
    ushort8 v;
    v[0] = f2bf(a.x); v[1] = f2bf(a.y); v[2] = f2bf(a.z); v[3] = f2bf(a.w);
    v[4] = f2bf(b.x); v[5] = f2bf(b.y); v[6] = f2bf(b.z); v[7] = f2bf(b.w);
    *(ushort8*)(Wd + g) = v;
  }
}

// ------------------------------- fp16 GEMM ---------------------------------
// LDS (halves): buffer d at d*32768; A kh at +kh*8192, B kh at
// +16384+kh*8192 (kh = K-half of 32). Per-kh layout: 1024 slots of 8
// halves; phys slot i holds logical chunk i^((i>>3)&3); read logical chunk
// c of row r at phys c^((r>>1)&3). 16x16 quarter read pattern -> 0 bank
// conflicts (measured R3..R13). Body t: stage(t+1) into buf (t+1)&1 (its
// last readers finished before the end-of-body-(t-1) barrier), compute
// both K-halves of tile t, vmcnt(0) drain, barrier. Prologue keeps
// wait->barrier (R4 lesson: vmcnt is per-wave; frag reads span waves).

#define STAGE64(T)                                                             \
  do {                                                                         \
    const int bb_ = ((T) & 1) * 32768;                                         \
    const int kk_ = (T) * 64;                                                  \
    gload_lds16(aSrc + kk_, ldsbuf + bb_ + dstL);                              \
    gload_lds16(aSrc + kk_ + 32, ldsbuf + bb_ + 8192 + dstL);                  \
    gload_lds16(bSrc + kk_, ldsbuf + bb_ + 16384 + dstL);                      \
    gload_lds16(bSrc + kk_ + 32, ldsbuf + bb_ + 24576 + dstL);                 \
  } while (0)

#define HALF_COMPUTE(T, KH)                                                    \
  do {                                                                         \
    const int ab_ = ((T) & 1) * 32768 + (KH) * 8192;                           \
    half8 bf[4], af[4];                                                        \
    _Pragma("unroll") for (int nj = 0; nj < 4; ++nj)                           \
        bf[nj] = *(const half8*)(ldsbuf + ab_ + 16384 + bBase + nj * 512);     \
    _Pragma("unroll") for (int mi = 0; mi < 4; ++mi)                           \
        af[mi] = *(const half8*)(ldsbuf + ab_ + aBase + mi * 512);             \
    __builtin_amdgcn_s_setprio(1);                                             \
    _Pragma("unroll") for (int mi = 0; mi < 4; ++mi)                           \
        _Pragma("unroll") for (int nj = 0; nj < 4; ++nj)                       \
        acc[mi][nj] = __builtin_amdgcn_mfma_f32_16x16x32_f16(                  \
            af[mi], bf[nj], acc[mi][nj], 0, 0, 0);                             \
    __builtin_amdgcn_s_setprio(0);                                             \
  } while (0)

#define BODY64(T, DOSTAGE)                                                     \
  do {                                                                         \
    if (DOSTAGE) STAGE64((T) + 1);                                             \
    HALF_COMPUTE(T, 0);                                                        \
    HALF_COMPUTE(T, 1);                                                        \
    asm volatile("s_waitcnt vmcnt(0)" ::: "memory");                           \
    __builtin_amdgcn_s_barrier();                                              \
    asm volatile("" ::: "memory");                                             \
  } while (0)

__global__ __launch_bounds__(1024, 4) void gemm_f16(
    const _Float16* __restrict__ A, const _Float16* __restrict__ Bt,
    const float* __restrict__ latent_bias, _Float16* __restrict__ C) {
  extern __shared__ _Float16 ldsbuf[];   // 2 bufs x 32768 halves

  const int tid = threadIdx.x;
  const int lane = tid & 63, wave = tid >> 6;   // wave 0..15
  const int wm = wave >> 2, wn = wave & 3;      // 4M x 4N

  int bid = blockIdx.x;
  int swz = (bid & 7) * (1024 >> 3) + (bid >> 3);
  const int bmBase = (swz >> 4) * 256;
  const int bnBase = (swz & 15) * 256;

  const int s = tid ^ ((tid >> 3) & 3);
  const _Float16* aSrc = A + (size_t)(bmBase + (s >> 2)) * D_DIM + (s & 3) * 8;
  const _Float16* bSrc = Bt + (size_t)(bnBase + (s >> 2)) * D_DIM + (s & 3) * 8;
  const int dstL = tid * 8;

  const int fr = lane & 15, c4 = lane >> 4;
  const int swzc = (c4 ^ ((fr >> 1) & 3)) * 8;
  const int aBase = (wm * 64 + fr) * 32 + swzc;
  const int bBase = (wn * 64 + fr) * 32 + swzc;

  f32x4 acc[4][4];
  #pragma unroll
  for (int i = 0; i < 4; ++i)
    #pragma unroll
    for (int j = 0; j < 4; ++j) acc[i][j] = f32x4{0.f, 0.f, 0.f, 0.f};

  // prologue: stage tile 0; wait own loads; barrier (cross-wave visibility)
  STAGE64(0);
  asm volatile("s_waitcnt vmcnt(0)" ::: "memory");
  __builtin_amdgcn_s_barrier();
  asm volatile("" ::: "memory");

  for (int t = 0; t < KT64 - 1; ++t) BODY64(t, true);
  BODY64(KT64 - 1, false);

  const int crow0 = bmBase + wm * 64 + c4 * 4;
  const int ccol0 = bnBase + wn * 64 + fr;
  #pragma unroll
  for (int mi = 0; mi < 4; ++mi)
    #pragma unroll
    for (int nj = 0; nj < 4; ++nj) {
      int col = ccol0 + nj * 16;
      float lb = latent_bias[col];
      #pragma unroll
      for (int r = 0; r < 4; ++r)
        C[(size_t)(crow0 + mi * 16 + r) * D_DIM + col] =
            (_Float16)(acc[mi][nj][r] + lb);
    }
}

// ------------- fused two-level-histogram top-k + fp64 rescue ---------------
// acts fp16 (quantization +-0.0625 at |v|<256); MARGIN=0.25 covers GEMM
// error (~0.16, 6-sigma) + quantization. Coarse 256 x 4.0 -> rank-refined
// fine 256 x 0.015625 -> T64 bracket [Tlo,Thi). Members: v > Thi+M
// (provably in exact top-64, < 64 of them). Zone: [Tlo-M, Thi+M]. Fast
// path: |zone| == need -> emit. Else fp64 dots (wave-per-candidate).

__global__ __launch_bounds__(256) void topk_full(
    const _Float16* __restrict__ acts, const float* __restrict__ x,
    const float* __restrict__ WT, const float* __restrict__ pre_bias,
    const float* __restrict__ latent_bias, float* __restrict__ vals,
    int* __restrict__ idxs) {
  const int row = blockIdx.x;
  const int tid = threadIdx.x;
  const int lane = tid & 63, wave = tid >> 6;
  __shared__ int hist[256];
  __shared__ int suf[256];
  __shared__ int sred[8];
  __shared__ int ambL[128];
  __shared__ double exv[128];
  const _Float16* arow = acts + (size_t)row * D_DIM;
  float fv[16];
  {
    half8 h0 = *(const half8*)(arow + tid * 8);
    half8 h1 = *(const half8*)(arow + 2048 + tid * 8);
    #pragma unroll
    for (int j = 0; j < 8; ++j) {
      fv[j] = (float)h0[j];
      fv[8 + j] = (float)h1[j];
    }
  }
  // ---- coarse pass ----
  hist[tid] = 0;
  __syncthreads();
  #pragma unroll
  for (int e = 0; e < 16; ++e) {
    int b = (int)((fv[e] + 512.0f) * 0.25f);
    b = b < 0 ? 0 : (b > 255 ? 255 : b);
    atomicAdd(&hist[b], 1);
  }
  __syncthreads();
  int c = hist[tid];
  int sfx = c;
  #pragma unroll
  for (int off = 1; off < 64; off <<= 1) {
    int y = __shfl_down(sfx, off);
    if (lane + off < 64) sfx += y;
  }
  if (lane == 0) sred[wave] = sfx;
  __syncthreads();
  {
    int after = 0;
    for (int w = wave + 1; w < 4; ++w) after += sred[w];
    sfx += after;  // count of values in bins >= tid
  }
  suf[tid] = sfx;
  int cnd = (sfx >= TOPK) ? tid : -1;
  #pragma unroll
  for (int off = 32; off; off >>= 1) {
    int y = __shfl_down(cnd, off);
    cnd = y > cnd ? y : cnd;
  }
  if (lane == 0) sred[4 + wave] = cnd;
  __syncthreads();
  int cb;
  {
    int m0 = sred[4] > sred[5] ? sred[4] : sred[5];
    int m1 = sred[6] > sred[7] ? sred[6] : sred[7];
    cb = m0 > m1 ? m0 : m1;  // exists: suffix(0) = 4096 >= 64
  }
  const int S_above = (cb < 255) ? suf[cb + 1] : 0;
  const int rrank = TOPK - S_above;  // in [1, count(cb)]
  const float Clo = cb * 4.0f - 512.0f;
  // ---- fine pass (reuse hist/sred) ----
  __syncthreads();
  hist[tid] = 0;
  __syncthreads();
  #pragma unroll
  for (int e = 0; e < 16; ++e) {
    int bc = (int)((fv[e] + 512.0f) * 0.25f);
    bc = bc < 0 ? 0 : (bc > 255 ? 255 : bc);
    if (bc == cb) {
      int fb = (int)((fv[e] - Clo) * 64.0f);
      fb = fb < 0 ? 0 : (fb > 255 ? 255 : fb);
      atomicAdd(&hist[fb], 1);
    }
  }
  __syncthreads();
  int cf = hist[tid];
  int sfx2 = cf;
  #pragma unroll
  for (int off = 1; off < 64; off <<= 1) {
    int y = __shfl_down(sfx2, off);
    if (lane + off < 64) sfx2 += y;
  }
  if (lane == 0) sred[wave] = sfx2;
  __syncthreads();
  {
    int after = 0;
    for (int w = wave + 1; w < 4; ++w) after += sred[w];
    sfx2 += after;
  }
  int cnd2 = (sfx2 >= rrank) ? tid : -1;
  #pragma unroll
  for (int off = 32; off; off >>= 1) {
    int y = __shfl_down(cnd2, off);
    cnd2 = y > cnd2 ? y : cnd2;
  }
  if (lane == 0) sred[4 + wave] = cnd2;
  __syncthreads();
  int fb;
  {
    int m0 = sred[4] > sred[5] ? sred[4] : sred[5];
    int m1 = sred[6] > sred[7] ? sred[6] : sred[7];
    fb = m0 > m1 ? m0 : m1;  // exists: fine suffix(0) = count(cb) >= rrank
  }
  const float Tlo = (cb == 0 && fb == 0) ? -1e30f : (Clo + fb * 0.015625f);
  const float Thi =
      (cb == 255 && fb == 255) ? 1e30f : (Clo + (fb + 1) * 0.015625f);
  const float vhi = Thi + MARGIN;
  const float vlo = Tlo - MARGIN;
  // ---- classify + emit ----
  int mC = 0, aC = 0;
  #pragma unroll
  for (int i = 0; i < 16; ++i) {
    float v = fv[i];
    if (v > vhi) ++mC;
    else if (v >= vlo) ++aC;
  }
  int xs = mC | (aC << 16);
  #pragma unroll
  for (int off = 1; off < 64; off <<= 1) {
    int y = __shfl_up(xs, off);
    if (lane >= off) xs += y;
  }
  __syncthreads();  // sred reuse
  if (lane == 63) sred[wave] = xs;
  __syncthreads();
  int base = 0;
  for (int w = 0; w < 4; ++w)
    if (w < wave) base += sred[w];
  int tot = sred[0] + sred[1] + sred[2] + sred[3];
  int incl = base + xs;
  int mp = (incl & 0xffff) - mC;
  int ap = (incl >> 16) - aC;
  int mTot = tot & 0xffff, aTot = tot >> 16;
  const int need = TOPK - mTot;      // >= 1 provably
  const bool fast = (aTot == need);  // zone exactly fills the remainder
  #pragma unroll
  for (int e = 0; e < 16; ++e) {
    float v = fv[e];
    int d = (e < 8) ? (tid * 8 + e) : (2048 + tid * 8 + (e - 8));
    if (v > vhi) {
      vals[(size_t)row * TOPK + mp] = fmaxf(v, 0.0f);
      idxs[(size_t)row * TOPK + mp] = d;
      ++mp;
    } else if (v >= vlo) {
      if (fast) {
        vals[(size_t)row * TOPK + mTot + ap] = fmaxf(v, 0.0f);
        idxs[(size_t)row * TOPK + mTot + ap] = d;
      } else if (ap < 128) {
        ambL[ap] = d;
      }
      ++ap;
    }
  }
  if (fast) return;
  // ---- fused fp64 rescue ----
  __syncthreads();  // ambL visible block-wide
  const int sN = aTot > 128 ? 128 : aTot;
  const float* xr = x + (size_t)row * D_DIM;
  for (int cc = wave; cc < sN; cc += 4) {
    int d = ambL[cc];
    const float* wrow = WT + (size_t)d * D_DIM;
    double acc = 0.0;
    #pragma unroll 4
    for (int t = 0; t < 16; ++t) {
      int k0 = t * 256 + lane * 4;
      float4 xv = *(const float4*)(xr + k0);
      float4 pv = *(const float4*)(pre_bias + k0);
      float4 wv = *(const float4*)(wrow + k0);
      acc = fma((double)xv.x - (double)pv.x, (double)wv.x, acc);
      acc = fma((double)xv.y - (double)pv.y, (double)wv.y, acc);
      acc = fma((double)xv.z - (double)pv.z, (double)wv.z, acc);
      acc = fma((double)xv.w - (double)pv.w, (double)wv.w, acc);
    }
    #pragma unroll
    for (int off = 32; off; off >>= 1) acc += __shfl_down(acc, off);
    if (lane == 0) exv[cc] = acc + (double)latent_bias[d];
  }
  __syncthreads();
  if (tid == 0) {
    for (int t = 0; t < need; ++t) {
      double best = -1.0e300; int besti = 1 << 30; int bestc = -1;
      for (int cc = 0; cc < sN; ++cc) {
        double v = exv[cc];
        int d = ambL[cc];
        if (v > best || (v == best && d < besti)) {
          best = v; besti = d; bestc = cc;
        }
      }
      vals[(size_t)row * TOPK + mTot + t] = fmaxf((float)best, 0.0f);
      idxs[(size_t)row * TOPK + mTot + t] = besti;
      exv[bestc] = -1.0e300;
    }
  }
}

// ----------------------------- reconstruct ---------------------------------

__global__ __launch_bounds__(256) void reconstruct(
    const unsigned short* __restrict__ Wd, const float* __restrict__ vals,
    const int* __restrict__ idxs, const float* __restrict__ pre_bias,
    float* __restrict__ out) {
  const int bid = blockIdx.x;
  const int cb = bid & 7, rowblk = bid >> 3;
  const int tid = threadIdx.x, lane = tid & 63, wave = tid >> 6;
  const int row = rowblk * 4 + wave;
  const int col0 = cb * 512 + lane * 8;
  __shared__ float sval[256];
  __shared__ int sidx[256];
  sval[tid] = vals[(size_t)(rowblk * 4 + (tid >> 6)) * TOPK + (tid & 63)];
  sidx[tid] = idxs[(size_t)(rowblk * 4 + (tid >> 6)) * TOPK + (tid & 63)];
  __syncthreads();
  float acc[8];
  float4 p0 = *(const float4*)(pre_bias + col0);
  float4 p1 = *(const float4*)(pre_bias + col0 + 4);
  acc[0] = p0.x; acc[1] = p0.y; acc[2] = p0.z; acc[3] = p0.w;
  acc[4] = p1.x; acc[5] = p1.y; acc[6] = p1.z; acc[7] = p1.w;
  #pragma unroll 4
  for (int k = 0; k < TOPK; ++k) {
    float v = sval[wave * 64 + k];
    int d = sidx[wave * 64 + k];
    ushort8 w = *(const ushort8*)(Wd + (size_t)d * D_DIM + col0);
    #pragma unroll
    for (int j = 0; j < 8; ++j)
      acc[j] = fmaf(v, __uint_as_float(((unsigned)w[j]) << 16), acc[j]);
  }
  float4 o0 = {acc[0], acc[1], acc[2], acc[3]};
  float4 o1 = {acc[4], acc[5], acc[6], acc[7]};
  *(float4*)(out + (size_t)row * D_DIM + col0) = o0;
  *(float4*)(out + (size_t)row * D_DIM + col0 + 4) = o1;
}

// ------------------------------- launcher ----------------------------------

extern "C" void kernel_launch(void* const* d_in, const int* in_sizes, int n_in,
                              void* d_out, int out_size, void* d_ws,
                              size_t ws_size, hipStream_t stream) {
  const float* x           = (const float*)d_in[0];
  // d_in[1] = ema_frequency_counter (unused by reference)
  const float* W_enc       = (const float*)d_in[2];
  const float* W_dec       = (const float*)d_in[3];
  const float* pre_bias    = (const float*)d_in[4];
  const float* latent_bias = (const float*)d_in[5];
  float* out = (float*)d_out;
  // fp16 acts alias d_out's first half; fully consumed by topk_full before
  // reconstruct overwrites all of out.
  _Float16* actsH = (_Float16*)d_out;
  char* ws = (char*)d_ws;
  size_t off = 0;
  auto alloc = [&](size_t bytes) {
    size_t o = off;
    off = (off + bytes + 255) & ~(size_t)255;
    return o;
  };
  _Float16* Xh        = (_Float16*)(ws + alloc((size_t)B_ROWS * D_DIM * 2));
  _Float16* WhT       = (_Float16*)(ws + alloc((size_t)D_DIM * D_DIM * 2));
  float* WT           = (float*)(ws + alloc((size_t)D_DIM * D_DIM * 4));
  unsigned short* Wd  = (unsigned short*)(ws + alloc((size_t)D_DIM * D_DIM * 2));
  float* vals         = (float*)(ws + alloc((size_t)B_ROWS * TOPK * 4));
  int* idxs           = (int*)(ws + alloc((size_t)B_ROWS * TOPK * 4));
  (void)ws_size; (void)in_sizes; (void)n_in; (void)out_size;

  // allow 128KB dynamic LDS for the GEMM (cheap, deterministic, idempotent)
  (void)hipFuncSetAttribute((const void*)gemm_f16,
                            hipFuncAttributeMaxDynamicSharedMemorySize,
                            131072);

  preprocess<<<45056, 256, 0, stream>>>(x, pre_bias, W_enc, W_dec,
                                        Xh, WhT, WT, Wd);
  gemm_f16<<<(B_ROWS / 256) * (D_DIM / 256), 1024, 131072, stream>>>(
      Xh, WhT, latent_bias, actsH);
  topk_full<<<B_ROWS, 256, 0, stream>>>(actsH, x, WT, pre_bias, latent_bias,
                                        vals, idxs);
  reconstruct<<<(B_ROWS / 4) * 8, 256, 0, stream>>>(Wd, vals, idxs, pre_bias,
                                                    out);
}